// Round 20
// baseline (104.880 us; speedup 1.0000x reference)
//
#include <hip/hip_runtime.h>
#include <stdint.h>

#define T_DIM 8192
#define J_DIM 1024
#define D_DIM 256

typedef __bf16 bf16x8 __attribute__((ext_vector_type(8)));
typedef float f32x4 __attribute__((ext_vector_type(4)));
typedef unsigned short u16x8 __attribute__((ext_vector_type(8)));
typedef unsigned short u16x4 __attribute__((ext_vector_type(4)));

__device__ inline unsigned short f2bf(float x) {
    unsigned u = __builtin_bit_cast(unsigned, x);
    u += 0x7FFFu + ((u >> 16) & 1u);
    return (unsigned short)(u >> 16);
}

// async global->LDS, 16B/lane; LDS dest = wave-uniform base + lane*16 (linear);
// swizzle applied on the per-lane GLOBAL source address (both-sides rule #21).
__device__ inline void gll16(const void* g, void* l) {
    __builtin_amdgcn_global_load_lds(
        (const __attribute__((address_space(1))) unsigned int*)g,
        (__attribute__((address_space(3))) unsigned int*)l, 16, 0, 0);
}

// K0: fused prep. Blocks [0,2048): ctx -> Cm bf16 + cw. [2048,2304): qry -> Qb,QT,qw.
// [2304,2370): zero stats (lsum|rmax|ht|done[128]|htdone).
__global__ __launch_bounds__(256) void prep_all(const float* __restrict__ ctx,
                                                const float* __restrict__ qry,
                                                const float* __restrict__ w,
                                                unsigned short* __restrict__ Cm,
                                                float* __restrict__ cw,
                                                unsigned short* __restrict__ Qb,
                                                unsigned short* __restrict__ QT,
                                                float* __restrict__ qw,
                                                float* __restrict__ stats) {
    int wid = threadIdx.x >> 6, lane = threadIdx.x & 63;
    if (blockIdx.x >= 2304) {
        int idx = (blockIdx.x - 2304) * 256 + threadIdx.x;
        if (idx < 2 * T_DIM + D_DIM + 129) stats[idx] = 0.0f;
        return;
    }
    if (blockIdx.x < 2048) {
        int t = blockIdx.x * 4 + wid;
        float4 c  = *(const float4*)(ctx + (size_t)t * D_DIM + lane * 4);
        float4 wm = *(const float4*)(w + 2 * D_DIM + lane * 4);
        float4 wc = *(const float4*)(w + lane * 4);
        u16x4 cmv;
        cmv[0] = f2bf(c.x * wm.x);
        cmv[1] = f2bf(c.y * wm.y);
        cmv[2] = f2bf(c.z * wm.z);
        cmv[3] = f2bf(c.w * wm.w);
        *(u16x4*)(Cm + (size_t)t * D_DIM + lane * 4) = cmv;
        float s = c.x * wc.x + c.y * wc.y + c.z * wc.z + c.w * wc.w;
        #pragma unroll
        for (int o = 1; o < 64; o <<= 1) s += __shfl_xor(s, o);
        if (lane == 0) cw[t] = s;
    } else {
        int j = (blockIdx.x - 2048) * 4 + wid;
        float4 c  = *(const float4*)(qry + (size_t)j * D_DIM + lane * 4);
        float4 wq = *(const float4*)(w + D_DIM + lane * 4);
        u16x4 qv;
        qv[0] = f2bf(c.x);
        qv[1] = f2bf(c.y);
        qv[2] = f2bf(c.z);
        qv[3] = f2bf(c.w);
        *(u16x4*)(Qb + (size_t)j * D_DIM + lane * 4) = qv;
        int d0 = lane * 4;
        QT[(size_t)(d0 + 0) * J_DIM + j] = qv[0];
        QT[(size_t)(d0 + 1) * J_DIM + j] = qv[1];
        QT[(size_t)(d0 + 2) * J_DIM + j] = qv[2];
        QT[(size_t)(d0 + 3) * J_DIM + j] = qv[3];
        float s = c.x * wq.x + c.y * wq.y + c.z * wq.z + c.w * wq.w;
        #pragma unroll
        for (int o = 1; o < 64; o <<= 1) s += __shfl_xor(s, o);
        if (lane == 0) qw[j] = s;
    }
}

// K1: fused gemm_s + hb + gemm_o in ONE launch with per-stripe dataflow.
// bid [0,1024): gemm_s body (r9) + release-add done[bm] after P stores drained.
// bid [1024,1152): hb body — spin done[stripe]==8, compute b & ht, release htdone.
// bid [1152,1664): gemm_o body (r16) — spin done[bm]==8 before K-loop,
//                  spin htdone==128 before epilogue.
// Union LDS 25.6KB -> 6 blocks/CU; producers have lowest bids -> deadlock-free.
__global__ __launch_bounds__(256) void mega_gemm(const unsigned short* __restrict__ Cm,
                                                 const unsigned short* __restrict__ Qb,
                                                 const float* __restrict__ qw,
                                                 const unsigned short* __restrict__ QT,
                                                 const float* __restrict__ cw,
                                                 const float* __restrict__ ctx,
                                                 unsigned short* __restrict__ P,
                                                 float* __restrict__ lsum,
                                                 int* __restrict__ rmax,
                                                 float* __restrict__ ht,
                                                 unsigned int* __restrict__ done,
                                                 unsigned int* __restrict__ htdone,
                                                 float* __restrict__ G) {
    __shared__ char RAW[25600];
    int tid = threadIdx.x, lane = tid & 63, wv = tid >> 6;

    if (blockIdx.x < 1024) {
        // ================= gemm_s body (r9) =================
        unsigned short* SH = (unsigned short*)RAW;        // As [64][64] | Bs [128][64]
        unsigned short* As = SH;
        unsigned short* Bs = SH + 4096;
        float* statS0 = (float*)(RAW + 24576);            // [64]
        float* statS1 = statS0 + 64;
        float* statM0 = statS1 + 64;
        float* statM1 = statM0 + 64;
        int wm = wv >> 1, wn = wv & 1;
        int bm = blockIdx.x & 127, bn = blockIdx.x >> 7;
        int cidx = lane & 15, rgrp = lane >> 4;
        int srow8 = lane >> 3;
        int swzc = (lane & 7) ^ srow8;
        f32x4 acc[2][4] = {};

        const unsigned short* Asrc = Cm + (size_t)(bm * 64 + srow8) * 256 + (swzc << 3);
        const unsigned short* Bsrc = Qb + (size_t)(bn * 128 + srow8) * 256 + (swzc << 3);

        for (int k0 = 0; k0 < 256; k0 += 64) {
            if (k0) __syncthreads();
            #pragma unroll
            for (int i = 0; i < 2; ++i) {
                int g = wv * 2 + i;
                gll16(Asrc + (size_t)(g * 8) * 256 + k0, As + g * 512);
            }
            #pragma unroll
            for (int i = 0; i < 4; ++i) {
                int g = wv * 4 + i;
                gll16(Bsrc + (size_t)(g * 8) * 256 + k0, Bs + g * 512);
            }
            __syncthreads();
            #pragma unroll
            for (int ks = 0; ks < 2; ++ks) {
                int klo = ks * 4 + rgrp;
                bf16x8 af[2], bfr[4];
                #pragma unroll
                for (int m = 0; m < 2; ++m) {
                    int ra = wm * 32 + m * 16 + cidx;
                    af[m] = __builtin_bit_cast(bf16x8,
                            *(const u16x8*)(As + ra * 64 + ((klo ^ (ra & 7)) << 3)));
                }
                #pragma unroll
                for (int n = 0; n < 4; ++n) {
                    int rb = wn * 64 + n * 16 + cidx;
                    bfr[n] = __builtin_bit_cast(bf16x8,
                            *(const u16x8*)(Bs + rb * 64 + ((klo ^ (rb & 7)) << 3)));
                }
                #pragma unroll
                for (int m = 0; m < 2; ++m)
                    #pragma unroll
                    for (int n = 0; n < 4; ++n)
                        acc[m][n] = __builtin_amdgcn_mfma_f32_16x16x32_bf16(af[m], bfr[n], acc[m][n], 0, 0, 0);
            }
        }

        float qwv[4];
        #pragma unroll
        for (int n = 0; n < 4; ++n) qwv[n] = qw[bn * 128 + wn * 64 + n * 16 + cidx];
        #pragma unroll
        for (int m = 0; m < 2; ++m) {
            #pragma unroll
            for (int rg = 0; rg < 4; ++rg) {
                float s = 0.f, mx = 0.f;
                #pragma unroll
                for (int n = 0; n < 4; ++n) {
                    float p = __expf(acc[m][n][rg] + qwv[n]);
                    acc[m][n][rg] = p;
                    s += p;
                    mx = fmaxf(mx, p);
                }
                #pragma unroll
                for (int o = 1; o < 16; o <<= 1) {
                    s += __shfl_xor(s, o);
                    mx = fmaxf(mx, __shfl_xor(mx, o));
                }
                if (cidx == 0) {
                    int row = wm * 32 + m * 16 + rgrp * 4 + rg;
                    (wn ? statS1 : statS0)[row] = s;
                    (wn ? statM1 : statM0)[row] = mx;
                }
            }
        }
        __syncthreads();
        if (tid < 64) {
            atomicAdd(lsum + bm * 64 + tid, statS0[tid] + statS1[tid]);
            atomicMax(rmax + bm * 64 + tid,
                      __float_as_int(fmaxf(statM0[tid], statM1[tid])));
        }

        #pragma unroll
        for (int m = 0; m < 2; ++m)
            #pragma unroll
            for (int n = 0; n < 4; ++n)
                #pragma unroll
                for (int rg = 0; rg < 4; ++rg) {
                    int row = wm * 32 + m * 16 + rgrp * 4 + rg;
                    int col = wn * 64 + n * 16 + cidx;
                    SH[row * 128 + (((col >> 3) ^ (row & 7)) << 3) + (col & 7)] = f2bf(acc[m][n][rg]);
                }
        __syncthreads();
        #pragma unroll
        for (int i = 0; i < 4; ++i) {
            int r = i * 16 + (tid >> 4);
            int c8 = tid & 15;
            u16x8 v = *(const u16x8*)(SH + r * 128 + ((c8 ^ (r & 7)) << 3));
            *(u16x8*)(P + (size_t)(bm * 64 + r) * J_DIM + bn * 128 + c8 * 8) = v;
        }
        // drain this thread's stores, barrier, single release-add for the block
        asm volatile("s_waitcnt vmcnt(0)" ::: "memory");
        __syncthreads();
        if (tid == 0)
            __hip_atomic_fetch_add(&done[bm], 1u, __ATOMIC_RELEASE, __HIP_MEMORY_SCOPE_AGENT);
        return;
    }

    if (blockIdx.x < 1152) {
        // ================= hb body =================
        float* bsh = (float*)RAW;          // 64 floats
        int stripe = blockIdx.x - 1024;
        if (tid == 0) {
            while (__hip_atomic_load(&done[stripe], __ATOMIC_ACQUIRE, __HIP_MEMORY_SCOPE_AGENT) < 8u)
                __builtin_amdgcn_s_sleep(1);
        }
        __syncthreads();
        int t0b = stripe * 64;
        if (tid < 64)
            bsh[tid] = __logf(__int_as_float(rmax[t0b + tid])) + cw[t0b + tid];
        __syncthreads();
        float pb = 0.f;
        #pragma unroll 8
        for (int r = 0; r < 64; ++r)
            pb += bsh[r] * ctx[(size_t)(t0b + r) * D_DIM + tid];
        atomicAdd(ht + tid, pb);
        __syncthreads();
        if (tid == 0)
            __hip_atomic_fetch_add(htdone, 1u, __ATOMIC_RELEASE, __HIP_MEMORY_SCOPE_AGENT);
        return;
    }

    // ================= gemm_o body (r16) =================
    {
        unsigned short* As = (unsigned short*)RAW;        // [64][64]
        unsigned short* Bs = As + 4096;                   // [64][64]
        float* SH32 = (float*)RAW;                        // epilogue f32 [64][64]
        int obid = blockIdx.x - 1152;
        int wm = wv >> 1, wn = wv & 1;
        int bm = obid & 127, bn = obid >> 7;
        int cidx = lane & 15, rgrp = lane >> 4;
        int srow8 = lane >> 3;
        int swzc = (lane & 7) ^ srow8;
        f32x4 acc[2][2] = {};

        if (tid == 0) {
            while (__hip_atomic_load(&done[bm], __ATOMIC_ACQUIRE, __HIP_MEMORY_SCOPE_AGENT) < 8u)
                __builtin_amdgcn_s_sleep(1);
        }
        __syncthreads();

        const unsigned short* Ap = P  + (size_t)(bm * 64 + srow8) * J_DIM + (swzc << 3);
        const unsigned short* Bp = QT + (size_t)(bn * 64 + srow8) * J_DIM + (swzc << 3);

        for (int k0 = 0; k0 < 1024; k0 += 64) {
            if (k0) __syncthreads();
            #pragma unroll
            for (int i = 0; i < 2; ++i) {
                int g = wv * 2 + i;
                gll16(Ap + (size_t)(g * 8) * J_DIM + k0, As + g * 512);
            }
            #pragma unroll
            for (int i = 0; i < 2; ++i) {
                int g = wv * 2 + i;
                gll16(Bp + (size_t)(g * 8) * J_DIM + k0, Bs + g * 512);
            }
            __syncthreads();
            #pragma unroll
            for (int ks = 0; ks < 2; ++ks) {
                int klo = ks * 4 + rgrp;
                bf16x8 af[2], bfr[2];
                #pragma unroll
                for (int m = 0; m < 2; ++m) {
                    int ra = wm * 32 + m * 16 + cidx;
                    af[m] = __builtin_bit_cast(bf16x8,
                            *(const u16x8*)(As + ra * 64 + ((klo ^ (ra & 7)) << 3)));
                }
                #pragma unroll
                for (int n = 0; n < 2; ++n) {
                    int rb = wn * 32 + n * 16 + cidx;
                    bfr[n] = __builtin_bit_cast(bf16x8,
                            *(const u16x8*)(Bs + rb * 64 + ((klo ^ (rb & 7)) << 3)));
                }
                #pragma unroll
                for (int m = 0; m < 2; ++m)
                    #pragma unroll
                    for (int n = 0; n < 2; ++n)
                        acc[m][n] = __builtin_amdgcn_mfma_f32_16x16x32_bf16(af[m], bfr[n], acc[m][n], 0, 0, 0);
            }
        }

        if (tid == 0) {
            while (__hip_atomic_load(htdone, __ATOMIC_ACQUIRE, __HIP_MEMORY_SCOPE_AGENT) < 128u)
                __builtin_amdgcn_s_sleep(1);
        }
        __syncthreads();

        #pragma unroll
        for (int i = 0; i < 4; ++i) {
            int idx = tid + i * 256;
            int row = idx >> 4, c4 = idx & 15;
            int t = bm * 64 + row;
            int d = bn * 64 + c4 * 4;
            float4 c = *(const float4*)(ctx + (size_t)t * D_DIM + d);
            float4 h = *(const float4*)(ht + d);
            float* gr = G + (size_t)t * 1024;
            *(float4*)(gr + d) = c;
            float4 o3;
            o3.x = c.x * h.x; o3.y = c.y * h.y; o3.z = c.z * h.z; o3.w = c.w * h.w;
            *(float4*)(gr + 768 + d) = o3;
        }
        #pragma unroll
        for (int m = 0; m < 2; ++m) {
            #pragma unroll
            for (int rg = 0; rg < 4; ++rg) {
                int row = wm * 32 + m * 16 + rgrp * 4 + rg;
                float linv = 1.0f / lsum[bm * 64 + row];
                #pragma unroll
                for (int n = 0; n < 2; ++n) {
                    int col = wn * 32 + n * 16 + cidx;
                    int c4 = col >> 2, slot = c4 ^ (row & 15);
                    SH32[row * 64 + slot * 4 + (col & 3)] = acc[m][n][rg] * linv;
                }
            }
        }
        __syncthreads();
        #pragma unroll
        for (int i = 0; i < 4; ++i) {
            int idx = tid + i * 256;
            int row = idx >> 4, c4 = idx & 15;
            int slot = c4 ^ (row & 15);
            float4 v = *(const float4*)(SH32 + row * 64 + slot * 4);
            int t = bm * 64 + row;
            int d = bn * 64 + c4 * 4;
            float4 c = *(const float4*)(ctx + (size_t)t * D_DIM + d);
            float* gr = G + (size_t)t * 1024;
            *(float4*)(gr + 256 + d) = v;
            float4 o2;
            o2.x = c.x * v.x; o2.y = c.y * v.y; o2.z = c.z * v.z; o2.w = c.w * v.w;
            *(float4*)(gr + 512 + d) = o2;
        }
    }
}

extern "C" void kernel_launch(void* const* d_in, const int* in_sizes, int n_in,
                              void* d_out, int out_size, void* d_ws, size_t ws_size,
                              hipStream_t stream) {
    (void)in_sizes; (void)n_in; (void)out_size; (void)ws_size;
    const float* ctx = (const float*)d_in[0];
    const float* qry = (const float*)d_in[1];
    const float* w   = (const float*)d_in[2];
    float* G = (float*)d_out;
    char* ws = (char*)d_ws;

    constexpr size_t OFF_P  = 0;                                   // 16 MiB
    constexpr size_t OFF_CM = OFF_P  + (size_t)T_DIM * J_DIM * 2;  // 4 MiB
    constexpr size_t OFF_QB = OFF_CM + (size_t)T_DIM * D_DIM * 2;
    constexpr size_t OFF_QT = OFF_QB + (size_t)J_DIM * D_DIM * 2;
    constexpr size_t OFF_CW = OFF_QT + (size_t)D_DIM * J_DIM * 2;
    constexpr size_t OFF_QW = OFF_CW + (size_t)T_DIM * 4;
    constexpr size_t OFF_ST = OFF_QW + (size_t)J_DIM * 4;

    unsigned short* P  = (unsigned short*)(ws + OFF_P);
    unsigned short* Cm = (unsigned short*)(ws + OFF_CM);
    unsigned short* Qb = (unsigned short*)(ws + OFF_QB);
    unsigned short* QT = (unsigned short*)(ws + OFF_QT);
    float* cw    = (float*)(ws + OFF_CW);
    float* qw    = (float*)(ws + OFF_QW);
    float* stats = (float*)(ws + OFF_ST);
    float* lsum  = stats;                          // 8192
    float* rmax  = stats + T_DIM;                  // 8192 (float bits via int atomicMax)
    float* ht    = stats + 2 * T_DIM;              // 256
    unsigned int* done   = (unsigned int*)(stats + 2 * T_DIM + D_DIM);        // 128
    unsigned int* htdone = (unsigned int*)(stats + 2 * T_DIM + D_DIM + 128);  // 1

    prep_all<<<dim3(2370), 256, 0, stream>>>(ctx, qry, w, Cm, cw, Qb, QT, qw, stats);
    mega_gemm<<<dim3(1664), 256, 0, stream>>>(Cm, Qb, qw, QT, cw, ctx, P,
                                              lsum, (int*)rmax, ht, done, htdone, G);
}

// Round 21
// 46.501 us; speedup vs baseline: 2.2554x; 2.2554x over previous
//
#include <hip/hip_runtime.h>
#include <stdint.h>

#define T_DIM 8192
#define J_DIM 1024
#define D_DIM 256

typedef __bf16 bf16x8 __attribute__((ext_vector_type(8)));
typedef float f32x4 __attribute__((ext_vector_type(4)));
typedef unsigned short u16x8 __attribute__((ext_vector_type(8)));
typedef unsigned short u16x4 __attribute__((ext_vector_type(4)));

__device__ inline unsigned short f2bf(float x) {
    unsigned u = __builtin_bit_cast(unsigned, x);
    u += 0x7FFFu + ((u >> 16) & 1u);
    return (unsigned short)(u >> 16);
}

// async global->LDS, 16B/lane; LDS dest = wave-uniform base + lane*16 (linear);
// swizzle applied on the per-lane GLOBAL source address (both-sides rule #21).
__device__ inline void gll16(const void* g, void* l) {
    __builtin_amdgcn_global_load_lds(
        (const __attribute__((address_space(1))) unsigned int*)g,
        (__attribute__((address_space(3))) unsigned int*)l, 16, 0, 0);
}

// LDS chunk slot for logical k-chunk kc (0..15) in row r of a [*][128] u16 tile.
__device__ inline int swz16(int kc, int r) {
    return (kc & 8) | ((kc & 7) ^ (r & 7));
}

// K0: fused prep. Blocks [0,2048): ctx -> Cm bf16 + cw. [2048,2304): qry -> Qb,QT,qw.
// [2304,2369): zero stats (lsum|rmax|ht|done).
__global__ __launch_bounds__(256) void prep_all(const float* __restrict__ ctx,
                                                const float* __restrict__ qry,
                                                const float* __restrict__ w,
                                                unsigned short* __restrict__ Cm,
                                                float* __restrict__ cw,
                                                unsigned short* __restrict__ Qb,
                                                unsigned short* __restrict__ QT,
                                                float* __restrict__ qw,
                                                float* __restrict__ stats) {
    int wid = threadIdx.x >> 6, lane = threadIdx.x & 63;
    if (blockIdx.x >= 2304) {
        int idx = (blockIdx.x - 2304) * 256 + threadIdx.x;
        if (idx < 2 * T_DIM + D_DIM + 1) stats[idx] = 0.0f;
        return;
    }
    if (blockIdx.x < 2048) {
        int t = blockIdx.x * 4 + wid;
        float4 c  = *(const float4*)(ctx + (size_t)t * D_DIM + lane * 4);
        float4 wm = *(const float4*)(w + 2 * D_DIM + lane * 4);
        float4 wc = *(const float4*)(w + lane * 4);
        u16x4 cmv;
        cmv[0] = f2bf(c.x * wm.x);
        cmv[1] = f2bf(c.y * wm.y);
        cmv[2] = f2bf(c.z * wm.z);
        cmv[3] = f2bf(c.w * wm.w);
        *(u16x4*)(Cm + (size_t)t * D_DIM + lane * 4) = cmv;
        float s = c.x * wc.x + c.y * wc.y + c.z * wc.z + c.w * wc.w;
        #pragma unroll
        for (int o = 1; o < 64; o <<= 1) s += __shfl_xor(s, o);
        if (lane == 0) cw[t] = s;
    } else {
        int j = (blockIdx.x - 2048) * 4 + wid;
        float4 c  = *(const float4*)(qry + (size_t)j * D_DIM + lane * 4);
        float4 wq = *(const float4*)(w + D_DIM + lane * 4);
        u16x4 qv;
        qv[0] = f2bf(c.x);
        qv[1] = f2bf(c.y);
        qv[2] = f2bf(c.z);
        qv[3] = f2bf(c.w);
        *(u16x4*)(Qb + (size_t)j * D_DIM + lane * 4) = qv;
        int d0 = lane * 4;
        QT[(size_t)(d0 + 0) * J_DIM + j] = qv[0];
        QT[(size_t)(d0 + 1) * J_DIM + j] = qv[1];
        QT[(size_t)(d0 + 2) * J_DIM + j] = qv[2];
        QT[(size_t)(d0 + 3) * J_DIM + j] = qv[3];
        float s = c.x * wq.x + c.y * wq.y + c.z * wq.z + c.w * wq.w;
        #pragma unroll
        for (int o = 1; o < 64; o <<= 1) s += __shfl_xor(s, o);
        if (lane == 0) qw[j] = s;
    }
}

// K1: P = bf16(exp(Cm @ Qb^T + qw)) + fused row stats (atomics).
// 64x128 tile, BK=64, 4 waves (2m x 2n), grid 1024 (r9-identical, best measured).
__global__ __launch_bounds__(256) void gemm_s(const unsigned short* __restrict__ Cm,
                                              const unsigned short* __restrict__ Qb,
                                              const float* __restrict__ qw,
                                              unsigned short* __restrict__ P,
                                              float* __restrict__ lsum,
                                              int* __restrict__ rmax) {
    __shared__ unsigned short SH[12288];   // As [64][64] (4096) | Bs [128][64] (8192)
    __shared__ float statS[2][64];
    __shared__ float statM[2][64];
    unsigned short* As = SH;
    unsigned short* Bs = SH + 4096;
    int tid = threadIdx.x, lane = tid & 63, wv = tid >> 6;
    int wm = wv >> 1, wn = wv & 1;
    int bm = blockIdx.x & 127, bn = blockIdx.x >> 7;
    int cidx = lane & 15, rgrp = lane >> 4;
    int srow8 = lane >> 3;                 // row within 8-row group
    int swzc = (lane & 7) ^ srow8;         // inverse-swizzled source chunk
    f32x4 acc[2][4] = {};

    const unsigned short* Asrc = Cm + (size_t)(bm * 64 + srow8) * 256 + (swzc << 3);
    const unsigned short* Bsrc = Qb + (size_t)(bn * 128 + srow8) * 256 + (swzc << 3);

    for (int k0 = 0; k0 < 256; k0 += 64) {
        if (k0) __syncthreads();
        #pragma unroll
        for (int i = 0; i < 2; ++i) {      // A: 8 groups, 2 per wave
            int g = wv * 2 + i;
            gll16(Asrc + (size_t)(g * 8) * 256 + k0, As + g * 512);
        }
        #pragma unroll
        for (int i = 0; i < 4; ++i) {      // B: 16 groups, 4 per wave
            int g = wv * 4 + i;
            gll16(Bsrc + (size_t)(g * 8) * 256 + k0, Bs + g * 512);
        }
        __syncthreads();
        #pragma unroll
        for (int ks = 0; ks < 2; ++ks) {
            int klo = ks * 4 + rgrp;
            bf16x8 af[2], bfr[4];
            #pragma unroll
            for (int m = 0; m < 2; ++m) {
                int ra = wm * 32 + m * 16 + cidx;
                af[m] = __builtin_bit_cast(bf16x8,
                        *(const u16x8*)(As + ra * 64 + ((klo ^ (ra & 7)) << 3)));
            }
            #pragma unroll
            for (int n = 0; n < 4; ++n) {
                int rb = wn * 64 + n * 16 + cidx;
                bfr[n] = __builtin_bit_cast(bf16x8,
                        *(const u16x8*)(Bs + rb * 64 + ((klo ^ (rb & 7)) << 3)));
            }
            #pragma unroll
            for (int m = 0; m < 2; ++m)
                #pragma unroll
                for (int n = 0; n < 4; ++n)
                    acc[m][n] = __builtin_amdgcn_mfma_f32_16x16x32_bf16(af[m], bfr[n], acc[m][n], 0, 0, 0);
        }
    }

    // exp + per-row stats
    float qwv[4];
    #pragma unroll
    for (int n = 0; n < 4; ++n) qwv[n] = qw[bn * 128 + wn * 64 + n * 16 + cidx];
    #pragma unroll
    for (int m = 0; m < 2; ++m) {
        #pragma unroll
        for (int rg = 0; rg < 4; ++rg) {
            float s = 0.f, mx = 0.f;
            #pragma unroll
            for (int n = 0; n < 4; ++n) {
                float p = __expf(acc[m][n][rg] + qwv[n]);
                acc[m][n][rg] = p;
                s += p;
                mx = fmaxf(mx, p);
            }
            #pragma unroll
            for (int o = 1; o < 16; o <<= 1) {
                s += __shfl_xor(s, o);
                mx = fmaxf(mx, __shfl_xor(mx, o));
            }
            if (cidx == 0) {
                int row = wm * 32 + m * 16 + rgrp * 4 + rg;
                statS[wn][row] = s;
                statM[wn][row] = mx;
            }
        }
    }
    __syncthreads();
    if (tid < 64) {
        atomicAdd(lsum + bm * 64 + tid, statS[0][tid] + statS[1][tid]);
        atomicMax(rmax + bm * 64 + tid,
                  __float_as_int(fmaxf(statM[0][tid], statM[1][tid])));
    }

    // restage P tile [64][128] (swizzled) + coalesced u16x8 stores
    #pragma unroll
    for (int m = 0; m < 2; ++m)
        #pragma unroll
        for (int n = 0; n < 4; ++n)
            #pragma unroll
            for (int rg = 0; rg < 4; ++rg) {
                int row = wm * 32 + m * 16 + rgrp * 4 + rg;
                int col = wn * 64 + n * 16 + cidx;
                SH[row * 128 + (((col >> 3) ^ (row & 7)) << 3) + (col & 7)] = f2bf(acc[m][n][rg]);
            }
    __syncthreads();
    #pragma unroll
    for (int i = 0; i < 4; ++i) {
        int r = i * 16 + (tid >> 4);
        int c8 = tid & 15;
        u16x8 v = *(const u16x8*)(SH + r * 128 + ((c8 ^ (r & 7)) << 3));
        *(u16x8*)(P + (size_t)(bm * 64 + r) * J_DIM + bn * 128 + c8 * 8) = v;
    }
}

// K2: combined hb + gemm_o in one launch.
// bid < 128: hb body (b = log(rmax)+cw, ht atomicAdd), then release-increment done.
// bid >= 128: gemm_o tile (BK=128 body); acquire-spin on done==128 before the
// epilogue (ht only needed there; K-loop ~10us hides hb's ~1.5us -> no actual spin).
// Deadlock-safe: 640 blocks x ~32.3KB LDS -> 4 blocks/CU -> 1024 slots >= 640.
__global__ __launch_bounds__(256) void gemm_o_hb(const unsigned short* __restrict__ P,
                                                 const unsigned short* __restrict__ QT,
                                                 const float* __restrict__ lsum,
                                                 float* __restrict__ ht,
                                                 const float* __restrict__ rmaxf,
                                                 const float* __restrict__ cw,
                                                 const float* __restrict__ ctx,
                                                 unsigned int* __restrict__ done,
                                                 float* __restrict__ G) {
    __shared__ unsigned short SH[16384];   // As [64][128] | Bs [64][128]; epi: f32 [64][64]
    unsigned short* As = SH;
    unsigned short* Bs = SH + 8192;
    float* SH32 = (float*)SH;
    int tid = threadIdx.x, lane = tid & 63, wv = tid >> 6;

    if (blockIdx.x < 128) {
        // ---- hb body ----
        float* bsh = SH32;                 // 64 floats
        int t0b = blockIdx.x * 64;
        if (tid < 64) bsh[tid] = __logf(rmaxf[t0b + tid]) + cw[t0b + tid];
        __syncthreads();
        float pb = 0.f;
        #pragma unroll 8
        for (int r = 0; r < 64; ++r)
            pb += bsh[r] * ctx[(size_t)(t0b + r) * D_DIM + tid];
        atomicAdd(ht + tid, pb);
        __syncthreads();
        if (tid == 0)
            __hip_atomic_fetch_add(done, 1u, __ATOMIC_RELEASE, __HIP_MEMORY_SCOPE_AGENT);
        return;
    }

    int bid = blockIdx.x - 128;
    int wm = wv >> 1, wn = wv & 1;
    int bm = bid & 127, bn = bid >> 7;
    int cidx = lane & 15, rgrp = lane >> 4;
    int lrow4 = lane >> 4;                 // row within 4-row staging group
    int lch = lane & 15;                   // chunk within 128-col row
    f32x4 acc[2][2] = {};

    for (int k0 = 0; k0 < 1024; k0 += 128) {
        if (k0) __syncthreads();
        #pragma unroll
        for (int i = 0; i < 4; ++i) {      // A: 16 groups of 4 rows, 4/wave
            int g = wv * 4 + i;
            int rl = g * 4 + lrow4;
            gll16(P + (size_t)(bm * 64 + rl) * J_DIM + k0 + swz16(lch, rl) * 8,
                  As + g * 512);
        }
        #pragma unroll
        for (int i = 0; i < 4; ++i) {      // B: 16 groups, 4/wave
            int g = wv * 4 + i;
            int rl = g * 4 + lrow4;
            gll16(QT + (size_t)(bn * 64 + rl) * J_DIM + k0 + swz16(lch, rl) * 8,
                  Bs + g * 512);
        }
        __syncthreads();
        #pragma unroll
        for (int kw = 0; kw < 4; ++kw) {
            int klo = kw * 4 + rgrp;
            bf16x8 af[2], bfr[2];
            #pragma unroll
            for (int m = 0; m < 2; ++m) {
                int ra = wm * 32 + m * 16 + cidx;
                af[m] = __builtin_bit_cast(bf16x8,
                        *(const u16x8*)(As + ra * 128 + swz16(klo, ra) * 8));
            }
            #pragma unroll
            for (int n = 0; n < 2; ++n) {
                int rb = wn * 32 + n * 16 + cidx;
                bfr[n] = __builtin_bit_cast(bf16x8,
                        *(const u16x8*)(Bs + rb * 128 + swz16(klo, rb) * 8));
            }
            #pragma unroll
            for (int m = 0; m < 2; ++m)
                #pragma unroll
                for (int n = 0; n < 2; ++n)
                    acc[m][n] = __builtin_amdgcn_mfma_f32_16x16x32_bf16(af[m], bfr[n], acc[m][n], 0, 0, 0);
        }
    }

    // ---- wait for ht complete (in practice already done), then epilogue ----
    if (tid == 0) {
        while (__hip_atomic_load(done, __ATOMIC_ACQUIRE, __HIP_MEMORY_SCOPE_AGENT) < 128u) {}
    }
    __syncthreads();

    #pragma unroll
    for (int i = 0; i < 4; ++i) {
        int idx = tid + i * 256;
        int row = idx >> 4, c4 = idx & 15;
        int t = bm * 64 + row;
        int d = bn * 64 + c4 * 4;
        float4 c = *(const float4*)(ctx + (size_t)t * D_DIM + d);
        float4 h = *(const float4*)(ht + d);
        float* gr = G + (size_t)t * 1024;
        *(float4*)(gr + d) = c;
        float4 o3;
        o3.x = c.x * h.x; o3.y = c.y * h.y; o3.z = c.z * h.z; o3.w = c.w * h.w;
        *(float4*)(gr + 768 + d) = o3;
    }
    #pragma unroll
    for (int m = 0; m < 2; ++m) {
        #pragma unroll
        for (int rg = 0; rg < 4; ++rg) {
            int row = wm * 32 + m * 16 + rgrp * 4 + rg;
            float linv = 1.0f / lsum[bm * 64 + row];
            #pragma unroll
            for (int n = 0; n < 2; ++n) {
                int col = wn * 32 + n * 16 + cidx;
                int c4 = col >> 2, slot = c4 ^ (row & 15);
                SH32[row * 64 + slot * 4 + (col & 3)] = acc[m][n][rg] * linv;
            }
        }
    }
    __syncthreads();
    #pragma unroll
    for (int i = 0; i < 4; ++i) {
        int idx = tid + i * 256;
        int row = idx >> 4, c4 = idx & 15;
        int slot = c4 ^ (row & 15);
        float4 v = *(const float4*)(SH32 + row * 64 + slot * 4);
        int t = bm * 64 + row;
        int d = bn * 64 + c4 * 4;
        float4 c = *(const float4*)(ctx + (size_t)t * D_DIM + d);
        float* gr = G + (size_t)t * 1024;
        *(float4*)(gr + 256 + d) = v;
        float4 o2;
        o2.x = c.x * v.x; o2.y = c.y * v.y; o2.z = c.z * v.z; o2.w = c.w * v.w;
        *(float4*)(gr + 512 + d) = o2;
    }
}

extern "C" void kernel_launch(void* const* d_in, const int* in_sizes, int n_in,
                              void* d_out, int out_size, void* d_ws, size_t ws_size,
                              hipStream_t stream) {
    (void)in_sizes; (void)n_in; (void)out_size; (void)ws_size;
    const float* ctx = (const float*)d_in[0];
    const float* qry = (const float*)d_in[1];
    const float* w   = (const float*)d_in[2];
    float* G = (float*)d_out;
    char* ws = (char*)d_ws;

    constexpr size_t OFF_P  = 0;                                   // 16 MiB
    constexpr size_t OFF_CM = OFF_P  + (size_t)T_DIM * J_DIM * 2;  // 4 MiB
    constexpr size_t OFF_QB = OFF_CM + (size_t)T_DIM * D_DIM * 2;
    constexpr size_t OFF_QT = OFF_QB + (size_t)J_DIM * D_DIM * 2;
    constexpr size_t OFF_CW = OFF_QT + (size_t)D_DIM * J_DIM * 2;
    constexpr size_t OFF_QW = OFF_CW + (size_t)T_DIM * 4;
    constexpr size_t OFF_ST = OFF_QW + (size_t)J_DIM * 4;

    unsigned short* P  = (unsigned short*)(ws + OFF_P);
    unsigned short* Cm = (unsigned short*)(ws + OFF_CM);
    unsigned short* Qb = (unsigned short*)(ws + OFF_QB);
    unsigned short* QT = (unsigned short*)(ws + OFF_QT);
    float* cw    = (float*)(ws + OFF_CW);
    float* qw    = (float*)(ws + OFF_QW);
    float* stats = (float*)(ws + OFF_ST);
    float* lsum  = stats;                          // 8192
    float* rmax  = stats + T_DIM;                  // 8192 (float bits via int atomicMax)
    float* ht    = stats + 2 * T_DIM;              // 256
    unsigned int* done = (unsigned int*)(stats + 2 * T_DIM + D_DIM);  // 1

    prep_all<<<dim3(2369), 256, 0, stream>>>(ctx, qry, w, Cm, cw, Qb, QT, qw, stats);
    gemm_s<<<dim3(1024), 256, 0, stream>>>(Cm, Qb, qw, P, lsum, (int*)rmax);
    gemm_o_hb<<<dim3(640), 256, 0, stream>>>(P, QT, lsum, ht, rmax, cw, ctx, done, G);
}

// Round 22
// 45.605 us; speedup vs baseline: 2.2998x; 1.0197x over previous
//
#include <hip/hip_runtime.h>
#include <stdint.h>

#define T_DIM 8192
#define J_DIM 1024
#define D_DIM 256

typedef __bf16 bf16x8 __attribute__((ext_vector_type(8)));
typedef float f32x4 __attribute__((ext_vector_type(4)));
typedef unsigned short u16x8 __attribute__((ext_vector_type(8)));
typedef unsigned short u16x4 __attribute__((ext_vector_type(4)));

__device__ inline unsigned short f2bf(float x) {
    unsigned u = __builtin_bit_cast(unsigned, x);
    u += 0x7FFFu + ((u >> 16) & 1u);
    return (unsigned short)(u >> 16);
}

// async global->LDS, 16B/lane; LDS dest = wave-uniform base + lane*16 (linear);
// swizzle applied on the per-lane GLOBAL source address (both-sides rule #21).
__device__ inline void gll16(const void* g, void* l) {
    __builtin_amdgcn_global_load_lds(
        (const __attribute__((address_space(1))) unsigned int*)g,
        (__attribute__((address_space(3))) unsigned int*)l, 16, 0, 0);
}

// LDS chunk slot for logical k-chunk kc (0..15) in row r of a [*][128] u16 tile.
__device__ inline int swz16(int kc, int r) {
    return (kc & 8) | ((kc & 7) ^ (r & 7));
}

// K0: fused prep. Blocks [0,2048): ctx -> Cm bf16 + cw. [2048,2304): qry -> Qb,QT,qw.
// [2304,2369): zero stats (lsum|rmax|ht|done).
__global__ __launch_bounds__(256) void prep_all(const float* __restrict__ ctx,
                                                const float* __restrict__ qry,
                                                const float* __restrict__ w,
                                                unsigned short* __restrict__ Cm,
                                                float* __restrict__ cw,
                                                unsigned short* __restrict__ Qb,
                                                unsigned short* __restrict__ QT,
                                                float* __restrict__ qw,
                                                float* __restrict__ stats) {
    int wid = threadIdx.x >> 6, lane = threadIdx.x & 63;
    if (blockIdx.x >= 2304) {
        int idx = (blockIdx.x - 2304) * 256 + threadIdx.x;
        if (idx < 2 * T_DIM + D_DIM + 1) stats[idx] = 0.0f;
        return;
    }
    if (blockIdx.x < 2048) {
        int t = blockIdx.x * 4 + wid;
        float4 c  = *(const float4*)(ctx + (size_t)t * D_DIM + lane * 4);
        float4 wm = *(const float4*)(w + 2 * D_DIM + lane * 4);
        float4 wc = *(const float4*)(w + lane * 4);
        u16x4 cmv;
        cmv[0] = f2bf(c.x * wm.x);
        cmv[1] = f2bf(c.y * wm.y);
        cmv[2] = f2bf(c.z * wm.z);
        cmv[3] = f2bf(c.w * wm.w);
        *(u16x4*)(Cm + (size_t)t * D_DIM + lane * 4) = cmv;
        float s = c.x * wc.x + c.y * wc.y + c.z * wc.z + c.w * wc.w;
        #pragma unroll
        for (int o = 1; o < 64; o <<= 1) s += __shfl_xor(s, o);
        if (lane == 0) cw[t] = s;
    } else {
        int j = (blockIdx.x - 2048) * 4 + wid;
        float4 c  = *(const float4*)(qry + (size_t)j * D_DIM + lane * 4);
        float4 wq = *(const float4*)(w + D_DIM + lane * 4);
        u16x4 qv;
        qv[0] = f2bf(c.x);
        qv[1] = f2bf(c.y);
        qv[2] = f2bf(c.z);
        qv[3] = f2bf(c.w);
        *(u16x4*)(Qb + (size_t)j * D_DIM + lane * 4) = qv;
        int d0 = lane * 4;
        QT[(size_t)(d0 + 0) * J_DIM + j] = qv[0];
        QT[(size_t)(d0 + 1) * J_DIM + j] = qv[1];
        QT[(size_t)(d0 + 2) * J_DIM + j] = qv[2];
        QT[(size_t)(d0 + 3) * J_DIM + j] = qv[3];
        float s = c.x * wq.x + c.y * wq.y + c.z * wq.z + c.w * wq.w;
        #pragma unroll
        for (int o = 1; o < 64; o <<= 1) s += __shfl_xor(s, o);
        if (lane == 0) qw[j] = s;
    }
}

// K1: P = bf16(exp(Cm @ Qb^T + qw)) + fused row stats (atomics).
// 64x128 tile, BK=64, 4 waves (2m x 2n), grid 1024. r18 body EXCEPT the P-store:
// direct scalar u16 stores from accumulators (no LDS restage, 2 fewer barriers).
__global__ __launch_bounds__(256) void gemm_s(const unsigned short* __restrict__ Cm,
                                              const unsigned short* __restrict__ Qb,
                                              const float* __restrict__ qw,
                                              unsigned short* __restrict__ P,
                                              float* __restrict__ lsum,
                                              int* __restrict__ rmax) {
    __shared__ unsigned short SH[12288];   // As [64][64] (4096) | Bs [128][64] (8192)
    __shared__ float statS[2][64];
    __shared__ float statM[2][64];
    unsigned short* As = SH;
    unsigned short* Bs = SH + 4096;
    int tid = threadIdx.x, lane = tid & 63, wv = tid >> 6;
    int wm = wv >> 1, wn = wv & 1;
    int bm = blockIdx.x & 127, bn = blockIdx.x >> 7;
    int cidx = lane & 15, rgrp = lane >> 4;
    int srow8 = lane >> 3;                 // row within 8-row group
    int swzc = (lane & 7) ^ srow8;         // inverse-swizzled source chunk
    f32x4 acc[2][4] = {};

    const unsigned short* Asrc = Cm + (size_t)(bm * 64 + srow8) * 256 + (swzc << 3);
    const unsigned short* Bsrc = Qb + (size_t)(bn * 128 + srow8) * 256 + (swzc << 3);

    for (int k0 = 0; k0 < 256; k0 += 64) {
        if (k0) __syncthreads();
        #pragma unroll
        for (int i = 0; i < 2; ++i) {      // A: 8 groups, 2 per wave
            int g = wv * 2 + i;
            gll16(Asrc + (size_t)(g * 8) * 256 + k0, As + g * 512);
        }
        #pragma unroll
        for (int i = 0; i < 4; ++i) {      // B: 16 groups, 4 per wave
            int g = wv * 4 + i;
            gll16(Bsrc + (size_t)(g * 8) * 256 + k0, Bs + g * 512);
        }
        __syncthreads();
        #pragma unroll
        for (int ks = 0; ks < 2; ++ks) {
            int klo = ks * 4 + rgrp;
            bf16x8 af[2], bfr[4];
            #pragma unroll
            for (int m = 0; m < 2; ++m) {
                int ra = wm * 32 + m * 16 + cidx;
                af[m] = __builtin_bit_cast(bf16x8,
                        *(const u16x8*)(As + ra * 64 + ((klo ^ (ra & 7)) << 3)));
            }
            #pragma unroll
            for (int n = 0; n < 4; ++n) {
                int rb = wn * 64 + n * 16 + cidx;
                bfr[n] = __builtin_bit_cast(bf16x8,
                        *(const u16x8*)(Bs + rb * 64 + ((klo ^ (rb & 7)) << 3)));
            }
            #pragma unroll
            for (int m = 0; m < 2; ++m)
                #pragma unroll
                for (int n = 0; n < 4; ++n)
                    acc[m][n] = __builtin_amdgcn_mfma_f32_16x16x32_bf16(af[m], bfr[n], acc[m][n], 0, 0, 0);
        }
    }

    // exp + per-row stats + DIRECT P stores (no restage)
    float qwv[4];
    #pragma unroll
    for (int n = 0; n < 4; ++n) qwv[n] = qw[bn * 128 + wn * 64 + n * 16 + cidx];
    #pragma unroll
    for (int m = 0; m < 2; ++m) {
        #pragma unroll
        for (int rg = 0; rg < 4; ++rg) {
            int row = wm * 32 + m * 16 + rgrp * 4 + rg;
            unsigned short* prow = P + (size_t)(bm * 64 + row) * J_DIM + bn * 128;
            float s = 0.f, mx = 0.f;
            #pragma unroll
            for (int n = 0; n < 4; ++n) {
                float p = __expf(acc[m][n][rg] + qwv[n]);
                prow[wn * 64 + n * 16 + cidx] = f2bf(p);
                s += p;
                mx = fmaxf(mx, p);
            }
            #pragma unroll
            for (int o = 1; o < 16; o <<= 1) {
                s += __shfl_xor(s, o);
                mx = fmaxf(mx, __shfl_xor(mx, o));
            }
            if (cidx == 0) {
                statS[wn][row] = s;
                statM[wn][row] = mx;
            }
        }
    }
    __syncthreads();
    if (tid < 64) {
        atomicAdd(lsum + bm * 64 + tid, statS[0][tid] + statS[1][tid]);
        atomicMax(rmax + bm * 64 + tid,
                  __float_as_int(fmaxf(statM[0][tid], statM[1][tid])));
    }
}

// K2: combined hb + gemm_o in one launch (r18-identical).
// bid < 128: hb body; release-increment done. bid >= 128: gemm_o BK=128 tile;
// acquire-spin on done==128 before the epilogue.
__global__ __launch_bounds__(256) void gemm_o_hb(const unsigned short* __restrict__ P,
                                                 const unsigned short* __restrict__ QT,
                                                 const float* __restrict__ lsum,
                                                 float* __restrict__ ht,
                                                 const float* __restrict__ rmaxf,
                                                 const float* __restrict__ cw,
                                                 const float* __restrict__ ctx,
                                                 unsigned int* __restrict__ done,
                                                 float* __restrict__ G) {
    __shared__ unsigned short SH[16384];   // As [64][128] | Bs [64][128]; epi: f32 [64][64]
    unsigned short* As = SH;
    unsigned short* Bs = SH + 8192;
    float* SH32 = (float*)SH;
    int tid = threadIdx.x, lane = tid & 63, wv = tid >> 6;

    if (blockIdx.x < 128) {
        // ---- hb body ----
        float* bsh = SH32;                 // 64 floats
        int t0b = blockIdx.x * 64;
        if (tid < 64) bsh[tid] = __logf(rmaxf[t0b + tid]) + cw[t0b + tid];
        __syncthreads();
        float pb = 0.f;
        #pragma unroll 8
        for (int r = 0; r < 64; ++r)
            pb += bsh[r] * ctx[(size_t)(t0b + r) * D_DIM + tid];
        atomicAdd(ht + tid, pb);
        __syncthreads();
        if (tid == 0)
            __hip_atomic_fetch_add(done, 1u, __ATOMIC_RELEASE, __HIP_MEMORY_SCOPE_AGENT);
        return;
    }

    int bid = blockIdx.x - 128;
    int wm = wv >> 1, wn = wv & 1;
    int bm = bid & 127, bn = bid >> 7;
    int cidx = lane & 15, rgrp = lane >> 4;
    int lrow4 = lane >> 4;                 // row within 4-row staging group
    int lch = lane & 15;                   // chunk within 128-col row
    f32x4 acc[2][2] = {};

    for (int k0 = 0; k0 < 1024; k0 += 128) {
        if (k0) __syncthreads();
        #pragma unroll
        for (int i = 0; i < 4; ++i) {      // A: 16 groups of 4 rows, 4/wave
            int g = wv * 4 + i;
            int rl = g * 4 + lrow4;
            gll16(P + (size_t)(bm * 64 + rl) * J_DIM + k0 + swz16(lch, rl) * 8,
                  As + g * 512);
        }
        #pragma unroll
        for (int i = 0; i < 4; ++i) {      // B: 16 groups, 4/wave
            int g = wv * 4 + i;
            int rl = g * 4 + lrow4;
            gll16(QT + (size_t)(bn * 64 + rl) * J_DIM + k0 + swz16(lch, rl) * 8,
                  Bs + g * 512);
        }
        __syncthreads();
        #pragma unroll
        for (int kw = 0; kw < 4; ++kw) {
            int klo = kw * 4 + rgrp;
            bf16x8 af[2], bfr[2];
            #pragma unroll
            for (int m = 0; m < 2; ++m) {
                int ra = wm * 32 + m * 16 + cidx;
                af[m] = __builtin_bit_cast(bf16x8,
                        *(const u16x8*)(As + ra * 128 + swz16(klo, ra) * 8));
            }
            #pragma unroll
            for (int n = 0; n < 2; ++n) {
                int rb = wn * 32 + n * 16 + cidx;
                bfr[n] = __builtin_bit_cast(bf16x8,
                        *(const u16x8*)(Bs + rb * 128 + swz16(klo, rb) * 8));
            }
            #pragma unroll
            for (int m = 0; m < 2; ++m)
                #pragma unroll
                for (int n = 0; n < 2; ++n)
                    acc[m][n] = __builtin_amdgcn_mfma_f32_16x16x32_bf16(af[m], bfr[n], acc[m][n], 0, 0, 0);
        }
    }

    // ---- wait for ht complete (in practice already done), then epilogue ----
    if (tid == 0) {
        while (__hip_atomic_load(done, __ATOMIC_ACQUIRE, __HIP_MEMORY_SCOPE_AGENT) < 128u) {}
    }
    __syncthreads();

    #pragma unroll
    for (int i = 0; i < 4; ++i) {
        int idx = tid + i * 256;
        int row = idx >> 4, c4 = idx & 15;
        int t = bm * 64 + row;
        int d = bn * 64 + c4 * 4;
        float4 c = *(const float4*)(ctx + (size_t)t * D_DIM + d);
        float4 h = *(const float4*)(ht + d);
        float* gr = G + (size_t)t * 1024;
        *(float4*)(gr + d) = c;
        float4 o3;
        o3.x = c.x * h.x; o3.y = c.y * h.y; o3.z = c.z * h.z; o3.w = c.w * h.w;
        *(float4*)(gr + 768 + d) = o3;
    }
    #pragma unroll
    for (int m = 0; m < 2; ++m) {
        #pragma unroll
        for (int rg = 0; rg < 4; ++rg) {
            int row = wm * 32 + m * 16 + rgrp * 4 + rg;
            float linv = 1.0f / lsum[bm * 64 + row];
            #pragma unroll
            for (int n = 0; n < 2; ++n) {
                int col = wn * 32 + n * 16 + cidx;
                int c4 = col >> 2, slot = c4 ^ (row & 15);
                SH32[row * 64 + slot * 4 + (col & 3)] = acc[m][n][rg] * linv;
            }
        }
    }
    __syncthreads();
    #pragma unroll
    for (int i = 0; i < 4; ++i) {
        int idx = tid + i * 256;
        int row = idx >> 4, c4 = idx & 15;
        int slot = c4 ^ (row & 15);
        float4 v = *(const float4*)(SH32 + row * 64 + slot * 4);
        int t = bm * 64 + row;
        int d = bn * 64 + c4 * 4;
        float4 c = *(const float4*)(ctx + (size_t)t * D_DIM + d);
        float* gr = G + (size_t)t * 1024;
        *(float4*)(gr + 256 + d) = v;
        float4 o2;
        o2.x = c.x * v.x; o2.y = c.y * v.y; o2.z = c.z * v.z; o2.w = c.w * v.w;
        *(float4*)(gr + 512 + d) = o2;
    }
}

extern "C" void kernel_launch(void* const* d_in, const int* in_sizes, int n_in,
                              void* d_out, int out_size, void* d_ws, size_t ws_size,
                              hipStream_t stream) {
    (void)in_sizes; (void)n_in; (void)out_size; (void)ws_size;
    const float* ctx = (const float*)d_in[0];
    const float* qry = (const float*)d_in[1];
    const float* w   = (const float*)d_in[2];
    float* G = (float*)d_out;
    char* ws = (char*)d_ws;

    constexpr size_t OFF_P  = 0;                                   // 16 MiB
    constexpr size_t OFF_CM = OFF_P  + (size_t)T_DIM * J_DIM * 2;  // 4 MiB
    constexpr size_t OFF_QB = OFF_CM + (size_t)T_DIM * D_DIM * 2;
    constexpr size_t OFF_QT = OFF_QB + (size_t)J_DIM * D_DIM * 2;
    constexpr size_t OFF_CW = OFF_QT + (size_t)D_DIM * J_DIM * 2;
    constexpr size_t OFF_QW = OFF_CW + (size_t)T_DIM * 4;
    constexpr size_t OFF_ST = OFF_QW + (size_t)J_DIM * 4;

    unsigned short* P  = (unsigned short*)(ws + OFF_P);
    unsigned short* Cm = (unsigned short*)(ws + OFF_CM);
    unsigned short* Qb = (unsigned short*)(ws + OFF_QB);
    unsigned short* QT = (unsigned short*)(ws + OFF_QT);
    float* cw    = (float*)(ws + OFF_CW);
    float* qw    = (float*)(ws + OFF_QW);
    float* stats = (float*)(ws + OFF_ST);
    float* lsum  = stats;                          // 8192
    float* rmax  = stats + T_DIM;                  // 8192 (float bits via int atomicMax)
    float* ht    = stats + 2 * T_DIM;              // 256
    unsigned int* done = (unsigned int*)(stats + 2 * T_DIM + D_DIM);  // 1

    prep_all<<<dim3(2369), 256, 0, stream>>>(ctx, qry, w, Cm, cw, Qb, QT, qw, stats);
    gemm_s<<<dim3(1024), 256, 0, stream>>>(Cm, Qb, qw, P, lsum, (int*)rmax);
    gemm_o_hb<<<dim3(640), 256, 0, stream>>>(P, QT, lsum, ht, rmax, cw, ctx, done, G);
}

// Round 23
// 45.205 us; speedup vs baseline: 2.3201x; 1.0088x over previous
//
#include <hip/hip_runtime.h>
#include <stdint.h>

#define T_DIM 8192
#define J_DIM 1024
#define D_DIM 256

typedef __bf16 bf16x8 __attribute__((ext_vector_type(8)));
typedef float f32x4 __attribute__((ext_vector_type(4)));
typedef unsigned short u16x8 __attribute__((ext_vector_type(8)));
typedef unsigned short u16x4 __attribute__((ext_vector_type(4)));

__device__ inline unsigned short f2bf(float x) {
    unsigned u = __builtin_bit_cast(unsigned, x);
    u += 0x7FFFu + ((u >> 16) & 1u);
    return (unsigned short)(u >> 16);
}

// async global->LDS, 16B/lane; LDS dest = wave-uniform base + lane*16 (linear);
// swizzle applied on the per-lane GLOBAL source address (both-sides rule #21).
__device__ inline void gll16(const void* g, void* l) {
    __builtin_amdgcn_global_load_lds(
        (const __attribute__((address_space(1))) unsigned int*)g,
        (__attribute__((address_space(3))) unsigned int*)l, 16, 0, 0);
}

// LDS chunk slot for logical k-chunk kc (0..15) in row r of a [*][128] u16 tile.
__device__ inline int swz16(int kc, int r) {
    return (kc & 8) | ((kc & 7) ^ (r & 7));
}

// K0: fused prep. Blocks [0,2048): ctx -> Cm bf16 + cw. [2048,2304): qry -> Qb,QT,qw.
// [2304,2369): zero stats (lsum|rmax|ht|done).
__global__ __launch_bounds__(256) void prep_all(const float* __restrict__ ctx,
                                                const float* __restrict__ qry,
                                                const float* __restrict__ w,
                                                unsigned short* __restrict__ Cm,
                                                float* __restrict__ cw,
                                                unsigned short* __restrict__ Qb,
                                                unsigned short* __restrict__ QT,
                                                float* __restrict__ qw,
                                                float* __restrict__ stats) {
    int wid = threadIdx.x >> 6, lane = threadIdx.x & 63;
    if (blockIdx.x >= 2304) {
        int idx = (blockIdx.x - 2304) * 256 + threadIdx.x;
        if (idx < 2 * T_DIM + D_DIM + 1) stats[idx] = 0.0f;
        return;
    }
    if (blockIdx.x < 2048) {
        int t = blockIdx.x * 4 + wid;
        float4 c  = *(const float4*)(ctx + (size_t)t * D_DIM + lane * 4);
        float4 wm = *(const float4*)(w + 2 * D_DIM + lane * 4);
        float4 wc = *(const float4*)(w + lane * 4);
        u16x4 cmv;
        cmv[0] = f2bf(c.x * wm.x);
        cmv[1] = f2bf(c.y * wm.y);
        cmv[2] = f2bf(c.z * wm.z);
        cmv[3] = f2bf(c.w * wm.w);
        *(u16x4*)(Cm + (size_t)t * D_DIM + lane * 4) = cmv;
        float s = c.x * wc.x + c.y * wc.y + c.z * wc.z + c.w * wc.w;
        #pragma unroll
        for (int o = 1; o < 64; o <<= 1) s += __shfl_xor(s, o);
        if (lane == 0) cw[t] = s;
    } else {
        int j = (blockIdx.x - 2048) * 4 + wid;
        float4 c  = *(const float4*)(qry + (size_t)j * D_DIM + lane * 4);
        float4 wq = *(const float4*)(w + D_DIM + lane * 4);
        u16x4 qv;
        qv[0] = f2bf(c.x);
        qv[1] = f2bf(c.y);
        qv[2] = f2bf(c.z);
        qv[3] = f2bf(c.w);
        *(u16x4*)(Qb + (size_t)j * D_DIM + lane * 4) = qv;
        int d0 = lane * 4;
        QT[(size_t)(d0 + 0) * J_DIM + j] = qv[0];
        QT[(size_t)(d0 + 1) * J_DIM + j] = qv[1];
        QT[(size_t)(d0 + 2) * J_DIM + j] = qv[2];
        QT[(size_t)(d0 + 3) * J_DIM + j] = qv[3];
        float s = c.x * wq.x + c.y * wq.y + c.z * wq.z + c.w * wq.w;
        #pragma unroll
        for (int o = 1; o < 64; o <<= 1) s += __shfl_xor(s, o);
        if (lane == 0) qw[j] = s;
    }
}

// K1: P = bf16(exp(Cm @ Qb^T + qw)) + fused row stats (atomics).
// 64x128 tile, BK=64, 4 waves (2m x 2n), grid 1024, direct P stores (r22 best).
__global__ __launch_bounds__(256) void gemm_s(const unsigned short* __restrict__ Cm,
                                              const unsigned short* __restrict__ Qb,
                                              const float* __restrict__ qw,
                                              unsigned short* __restrict__ P,
                                              float* __restrict__ lsum,
                                              int* __restrict__ rmax) {
    __shared__ unsigned short SH[12288];   // As [64][64] (4096) | Bs [128][64] (8192)
    __shared__ float statS[2][64];
    __shared__ float statM[2][64];
    unsigned short* As = SH;
    unsigned short* Bs = SH + 4096;
    int tid = threadIdx.x, lane = tid & 63, wv = tid >> 6;
    int wm = wv >> 1, wn = wv & 1;
    int bm = blockIdx.x & 127, bn = blockIdx.x >> 7;
    int cidx = lane & 15, rgrp = lane >> 4;
    int srow8 = lane >> 3;                 // row within 8-row group
    int swzc = (lane & 7) ^ srow8;         // inverse-swizzled source chunk
    f32x4 acc[2][4] = {};

    const unsigned short* Asrc = Cm + (size_t)(bm * 64 + srow8) * 256 + (swzc << 3);
    const unsigned short* Bsrc = Qb + (size_t)(bn * 128 + srow8) * 256 + (swzc << 3);

    for (int k0 = 0; k0 < 256; k0 += 64) {
        if (k0) __syncthreads();
        #pragma unroll
        for (int i = 0; i < 2; ++i) {      // A: 8 groups, 2 per wave
            int g = wv * 2 + i;
            gll16(Asrc + (size_t)(g * 8) * 256 + k0, As + g * 512);
        }
        #pragma unroll
        for (int i = 0; i < 4; ++i) {      // B: 16 groups, 4 per wave
            int g = wv * 4 + i;
            gll16(Bsrc + (size_t)(g * 8) * 256 + k0, Bs + g * 512);
        }
        __syncthreads();
        #pragma unroll
        for (int ks = 0; ks < 2; ++ks) {
            int klo = ks * 4 + rgrp;
            bf16x8 af[2], bfr[4];
            #pragma unroll
            for (int m = 0; m < 2; ++m) {
                int ra = wm * 32 + m * 16 + cidx;
                af[m] = __builtin_bit_cast(bf16x8,
                        *(const u16x8*)(As + ra * 64 + ((klo ^ (ra & 7)) << 3)));
            }
            #pragma unroll
            for (int n = 0; n < 4; ++n) {
                int rb = wn * 64 + n * 16 + cidx;
                bfr[n] = __builtin_bit_cast(bf16x8,
                        *(const u16x8*)(Bs + rb * 64 + ((klo ^ (rb & 7)) << 3)));
            }
            #pragma unroll
            for (int m = 0; m < 2; ++m)
                #pragma unroll
                for (int n = 0; n < 4; ++n)
                    acc[m][n] = __builtin_amdgcn_mfma_f32_16x16x32_bf16(af[m], bfr[n], acc[m][n], 0, 0, 0);
        }
    }

    // exp + per-row stats + DIRECT P stores (no restage)
    float qwv[4];
    #pragma unroll
    for (int n = 0; n < 4; ++n) qwv[n] = qw[bn * 128 + wn * 64 + n * 16 + cidx];
    #pragma unroll
    for (int m = 0; m < 2; ++m) {
        #pragma unroll
        for (int rg = 0; rg < 4; ++rg) {
            int row = wm * 32 + m * 16 + rgrp * 4 + rg;
            unsigned short* prow = P + (size_t)(bm * 64 + row) * J_DIM + bn * 128;
            float s = 0.f, mx = 0.f;
            #pragma unroll
            for (int n = 0; n < 4; ++n) {
                float p = __expf(acc[m][n][rg] + qwv[n]);
                prow[wn * 64 + n * 16 + cidx] = f2bf(p);
                s += p;
                mx = fmaxf(mx, p);
            }
            #pragma unroll
            for (int o = 1; o < 16; o <<= 1) {
                s += __shfl_xor(s, o);
                mx = fmaxf(mx, __shfl_xor(mx, o));
            }
            if (cidx == 0) {
                statS[wn][row] = s;
                statM[wn][row] = mx;
            }
        }
    }
    __syncthreads();
    if (tid < 64) {
        atomicAdd(lsum + bm * 64 + tid, statS[0][tid] + statS[1][tid]);
        atomicMax(rmax + bm * 64 + tid,
                  __float_as_int(fmaxf(statM[0][tid], statM[1][tid])));
    }
}

// K2: combined hb + gemm_o in one launch.
// bid < 128: hb body; release-increment done. bid >= 128: gemm_o BK=128 tile;
// acquire-spin on done==128 before the epilogue. Epilogue: direct stores from
// acc (no LDS restage, 2 fewer barriers); cols 0,3 coalesced float4.
__global__ __launch_bounds__(256) void gemm_o_hb(const unsigned short* __restrict__ P,
                                                 const unsigned short* __restrict__ QT,
                                                 const float* __restrict__ lsum,
                                                 float* __restrict__ ht,
                                                 const float* __restrict__ rmaxf,
                                                 const float* __restrict__ cw,
                                                 const float* __restrict__ ctx,
                                                 unsigned int* __restrict__ done,
                                                 float* __restrict__ G) {
    __shared__ unsigned short SH[16384];   // As [64][128] | Bs [64][128]
    unsigned short* As = SH;
    unsigned short* Bs = SH + 8192;
    float* SH32 = (float*)SH;
    int tid = threadIdx.x, lane = tid & 63, wv = tid >> 6;

    if (blockIdx.x < 128) {
        // ---- hb body ----
        float* bsh = SH32;                 // 64 floats
        int t0b = blockIdx.x * 64;
        if (tid < 64) bsh[tid] = __logf(rmaxf[t0b + tid]) + cw[t0b + tid];
        __syncthreads();
        float pb = 0.f;
        #pragma unroll 8
        for (int r = 0; r < 64; ++r)
            pb += bsh[r] * ctx[(size_t)(t0b + r) * D_DIM + tid];
        atomicAdd(ht + tid, pb);
        __syncthreads();
        if (tid == 0)
            __hip_atomic_fetch_add(done, 1u, __ATOMIC_RELEASE, __HIP_MEMORY_SCOPE_AGENT);
        return;
    }

    int bid = blockIdx.x - 128;
    int wm = wv >> 1, wn = wv & 1;
    int bm = bid & 127, bn = bid >> 7;
    int cidx = lane & 15, rgrp = lane >> 4;
    int lrow4 = lane >> 4;                 // row within 4-row staging group
    int lch = lane & 15;                   // chunk within 128-col row
    f32x4 acc[2][2] = {};

    for (int k0 = 0; k0 < 1024; k0 += 128) {
        if (k0) __syncthreads();
        #pragma unroll
        for (int i = 0; i < 4; ++i) {      // A: 16 groups of 4 rows, 4/wave
            int g = wv * 4 + i;
            int rl = g * 4 + lrow4;
            gll16(P + (size_t)(bm * 64 + rl) * J_DIM + k0 + swz16(lch, rl) * 8,
                  As + g * 512);
        }
        #pragma unroll
        for (int i = 0; i < 4; ++i) {      // B: 16 groups, 4/wave
            int g = wv * 4 + i;
            int rl = g * 4 + lrow4;
            gll16(QT + (size_t)(bn * 64 + rl) * J_DIM + k0 + swz16(lch, rl) * 8,
                  Bs + g * 512);
        }
        __syncthreads();
        #pragma unroll
        for (int kw = 0; kw < 4; ++kw) {
            int klo = kw * 4 + rgrp;
            bf16x8 af[2], bfr[2];
            #pragma unroll
            for (int m = 0; m < 2; ++m) {
                int ra = wm * 32 + m * 16 + cidx;
                af[m] = __builtin_bit_cast(bf16x8,
                        *(const u16x8*)(As + ra * 128 + swz16(klo, ra) * 8));
            }
            #pragma unroll
            for (int n = 0; n < 2; ++n) {
                int rb = wn * 32 + n * 16 + cidx;
                bfr[n] = __builtin_bit_cast(bf16x8,
                        *(const u16x8*)(Bs + rb * 128 + swz16(klo, rb) * 8));
            }
            #pragma unroll
            for (int m = 0; m < 2; ++m)
                #pragma unroll
                for (int n = 0; n < 2; ++n)
                    acc[m][n] = __builtin_amdgcn_mfma_f32_16x16x32_bf16(af[m], bfr[n], acc[m][n], 0, 0, 0);
        }
    }

    // ---- wait for ht complete (in practice already done), then epilogue ----
    if (tid == 0) {
        while (__hip_atomic_load(done, __ATOMIC_ACQUIRE, __HIP_MEMORY_SCOPE_AGENT) < 128u) {}
    }
    __syncthreads();

    // G cols 0,3: coalesced float4 (independent of acc)
    #pragma unroll
    for (int i = 0; i < 4; ++i) {
        int idx = tid + i * 256;
        int row = idx >> 4, c4 = idx & 15;
        int t = bm * 64 + row;
        int d = bn * 64 + c4 * 4;
        float4 c = *(const float4*)(ctx + (size_t)t * D_DIM + d);
        float4 h = *(const float4*)(ht + d);
        float* gr = G + (size_t)t * 1024;
        *(float4*)(gr + d) = c;
        float4 o3;
        o3.x = c.x * h.x; o3.y = c.y * h.y; o3.z = c.z * h.z; o3.w = c.w * h.w;
        *(float4*)(gr + 768 + d) = o3;
    }
    // G cols 1,2: direct scalar stores from acc (no LDS restage)
    #pragma unroll
    for (int m = 0; m < 2; ++m) {
        #pragma unroll
        for (int rg = 0; rg < 4; ++rg) {
            int row = wm * 32 + m * 16 + rgrp * 4 + rg;
            int t = bm * 64 + row;
            float linv = 1.0f / lsum[t];
            float* gr = G + (size_t)t * 1024;
            #pragma unroll
            for (int n = 0; n < 2; ++n) {
                int d = bn * 64 + wn * 32 + n * 16 + cidx;
                float val = acc[m][n][rg] * linv;
                float c = ctx[(size_t)t * D_DIM + d];
                gr[256 + d] = val;
                gr[512 + d] = c * val;
            }
        }
    }
}

extern "C" void kernel_launch(void* const* d_in, const int* in_sizes, int n_in,
                              void* d_out, int out_size, void* d_ws, size_t ws_size,
                              hipStream_t stream) {
    (void)in_sizes; (void)n_in; (void)out_size; (void)ws_size;
    const float* ctx = (const float*)d_in[0];
    const float* qry = (const float*)d_in[1];
    const float* w   = (const float*)d_in[2];
    float* G = (float*)d_out;
    char* ws = (char*)d_ws;

    constexpr size_t OFF_P  = 0;                                   // 16 MiB
    constexpr size_t OFF_CM = OFF_P  + (size_t)T_DIM * J_DIM * 2;  // 4 MiB
    constexpr size_t OFF_QB = OFF_CM + (size_t)T_DIM * D_DIM * 2;
    constexpr size_t OFF_QT = OFF_QB + (size_t)J_DIM * D_DIM * 2;
    constexpr size_t OFF_CW = OFF_QT + (size_t)D_DIM * J_DIM * 2;
    constexpr size_t OFF_QW = OFF_CW + (size_t)T_DIM * 4;
    constexpr size_t OFF_ST = OFF_QW + (size_t)J_DIM * 4;

    unsigned short* P  = (unsigned short*)(ws + OFF_P);
    unsigned short* Cm = (unsigned short*)(ws + OFF_CM);
    unsigned short* Qb = (unsigned short*)(ws + OFF_QB);
    unsigned short* QT = (unsigned short*)(ws + OFF_QT);
    float* cw    = (float*)(ws + OFF_CW);
    float* qw    = (float*)(ws + OFF_QW);
    float* stats = (float*)(ws + OFF_ST);
    float* lsum  = stats;                          // 8192
    float* rmax  = stats + T_DIM;                  // 8192 (float bits via int atomicMax)
    float* ht    = stats + 2 * T_DIM;              // 256
    unsigned int* done = (unsigned int*)(stats + 2 * T_DIM + D_DIM);  // 1

    prep_all<<<dim3(2369), 256, 0, stream>>>(ctx, qry, w, Cm, cw, Qb, QT, qw, stats);
    gemm_s<<<dim3(1024), 256, 0, stream>>>(Cm, Qb, qw, P, lsum, (int*)rmax);
    gemm_o_hb<<<dim3(640), 256, 0, stream>>>(P, QT, lsum, ht, rmax, cw, ctx, done, G);
}